// Round 12
// baseline (562.000 us; speedup 1.0000x reference)
//
#include <hip/hip_runtime.h>

#define NN 50000
#define EE 800000
#define BB 500

typedef short v8s __attribute__((ext_vector_type(8)));
typedef float v4f __attribute__((ext_vector_type(4)));

__device__ __forceinline__ float bf2f(unsigned short u) {
    union { unsigned int i; float f; } v; v.i = ((unsigned int)u) << 16; return v.f;
}
__device__ __forceinline__ unsigned short f2bf(float f) {
    union { float f; unsigned int i; } v; v.f = f;
    unsigned int x = v.i;
    unsigned int r = (x + 0x7FFFu + ((x >> 16) & 1u)) >> 16;
    return (unsigned short)r;
}

// async global->LDS, 16B per lane; dst must be wave-uniform base (HW adds lane*16)
__device__ __forceinline__ void gll16(const unsigned short* g, v8s* l) {
    __builtin_amdgcn_global_load_lds((const __attribute__((address_space(1))) unsigned int*)g,
                                     (__attribute__((address_space(3))) unsigned int*)l, 16, 0, 0);
}

__global__ void k_sentinel(float* out, float val) {
    int i = blockIdx.x * blockDim.x + threadIdx.x;
    if (i < BB * 512) out[i] = val;
}

// fused: cursor init + node featurization + weight transposes + gcat zero (full 832)
__global__ void k_prep(const float* __restrict__ nf, const int* __restrict__ bmask,
                       const float* __restrict__ bboxW, const float* __restrict__ bboxb,
                       const float* __restrict__ membed, unsigned short* __restrict__ feat,
                       const float* __restrict__ a0, unsigned short* __restrict__ d0,
                       const float* __restrict__ a1, unsigned short* __restrict__ d1,
                       const float* __restrict__ a2, unsigned short* __restrict__ d2,
                       const float* __restrict__ a3, unsigned short* __restrict__ d3,
                       int* __restrict__ cur, float* __restrict__ gcat) {
    int g = blockIdx.x * blockDim.x + threadIdx.x;
    if (g < NN) cur[g] = 0;
    if (g < NN * 64) {
        int n = g >> 6, f = g & 63;
        float s = bboxb[f];
        for (int k = 0; k < 5; ++k) s += nf[n * 5 + k] * bboxW[k * 64 + f];
        s = fmaxf(s, 0.f);
        int bm = bmask[n]; if ((unsigned)bm > 1u) bm = 0;
        float mv = fmaxf(membed[bm * 64 + f], 0.f);
        feat[(size_t)n * 128 + f] = f2bf(s);
        feat[(size_t)n * 128 + 64 + f] = f2bf(mv);
        return;
    }
    g -= NN * 64;
    if (g >= 155648) {
        if (g < 155648 + BB * 832) {
            int idx = g - 155648;
            gcat[idx] = 0.f;  // atomicMax target init (all 832 cols)
        }
        return;
    }
    const float* in; unsigned short* out; int K, Nout, idx;
    if (g < 8192)        { in = a0; out = d0; K = 128; Nout = 64;  idx = g; }
    else if (g < 24576)  { in = a1; out = d1; K = 64;  Nout = 256; idx = g - 8192; }
    else if (g < 90112)  { in = a2; out = d2; K = 256; Nout = 256; idx = g - 24576; }
    else                 { in = a3; out = d3; K = 256; Nout = 256; idx = g - 90112; }
    int k = idx / Nout, n = idx % Nout;
    out[n * K + k] = f2bf(in[idx]);
}

// n0 GEMM (64x64 tile, R4/R5 form) with fused segment-max epilogue (R10).
template <int KT>
__global__ __launch_bounds__(256) void k_gemm(const unsigned short* __restrict__ A,
                                              const unsigned short* __restrict__ Bt,
                                              const float* __restrict__ bias,
                                              unsigned short* __restrict__ C, int M, int ldc,
                                              const int* __restrict__ batch, float* __restrict__ gmax) {
    constexpr int NT = KT / 64;
    constexpr int NB = (NT > 1) ? 2 : 1;
    __shared__ v8s As[NB][512];
    __shared__ v8s Bs[NB][512];
    const int t = threadIdx.x;
    const int bx = blockIdx.x;
    const int m0 = bx * 64;
    const int l = t & 63, w = t >> 6;
    const int q = l >> 4, r16 = l & 15;
    const int nloc = w * 16 + r16;

    const int roff0 = (w * 2 + 0) * 8 + (l >> 3);
    const int roff1 = (w * 2 + 1) * 8 + (l >> 3);
    const int kc = (l & 7) ^ (l >> 3);
    const unsigned short* Asrc0 = A + (size_t)(m0 + roff0) * KT + kc * 8;
    const unsigned short* Asrc1 = A + (size_t)(m0 + roff1) * KT + kc * 8;
    const unsigned short* Bsrc0 = Bt + (size_t)roff0 * KT + kc * 8;
    const unsigned short* Bsrc1 = Bt + (size_t)roff1 * KT + kc * 8;

    v4f acc[4];
#pragma unroll
    for (int i = 0; i < 4; ++i) acc[i] = (v4f){0.f, 0.f, 0.f, 0.f};

    gll16(Asrc0, &As[0][(w * 2 + 0) * 64]);
    gll16(Asrc1, &As[0][(w * 2 + 1) * 64]);
    gll16(Bsrc0, &Bs[0][(w * 2 + 0) * 64]);
    gll16(Bsrc1, &Bs[0][(w * 2 + 1) * 64]);
    __syncthreads();
#pragma unroll
    for (int kt = 0; kt < NT; ++kt) {
        const int b = kt & (NB - 1);
        if (kt + 1 < NT) {
            const int nb = (kt + 1) & (NB - 1);
            gll16(Asrc0 + (kt + 1) * 64, &As[nb][(w * 2 + 0) * 64]);
            gll16(Asrc1 + (kt + 1) * 64, &As[nb][(w * 2 + 1) * 64]);
            gll16(Bsrc0 + (kt + 1) * 64, &Bs[nb][(w * 2 + 0) * 64]);
            gll16(Bsrc1 + (kt + 1) * 64, &Bs[nb][(w * 2 + 1) * 64]);
        }
#pragma unroll
        for (int s = 0; s < 2; ++s) {
            int c = s * 4 + q;
            v8s bfr = Bs[b][nloc * 8 + (c ^ (nloc & 7))];
#pragma unroll
            for (int mt = 0; mt < 4; ++mt) {
                v8s afr = As[b][(mt * 16 + r16) * 8 + (c ^ (r16 & 7))];
                acc[mt] = __builtin_amdgcn_mfma_f32_16x16x32_bf16(afr, bfr, acc[mt], 0, 0, 0);
            }
        }
        __syncthreads();
    }

    const int col = nloc;
#pragma unroll
    for (int mt = 0; mt < 4; ++mt) {
#pragma unroll
        for (int r = 0; r < 4; ++r) {
            int row = m0 + mt * 16 + q * 4 + r;
            if (row < M) {
                float v = fmaxf(acc[mt][r] + bias[col], 0.f);
                C[(size_t)row * ldc + col] = f2bf(v);
                atomicMax((int*)(gmax + (size_t)batch[row] * 832 + col), __float_as_int(v));
            }
        }
    }
}

// R11: 128x128-tile ATT layer GEMM (N=256, ldc=256). 32 MFMA/wave/barrier (4x
// the old 64x64 -> barrier-drain stalls amortized), A traffic halved (2 col-
// tiles). Grid 784 = 49 groups x 16; bx = (p>>4)*8+(p&7), by = (p>>3)&1 so
// (bx,0)/(bx,1) land on the same XCD (p, p+8). LDS 80KB -> 2 blocks/CU.
// ATT epilogue re-derived: head = by*2+f; per-(mt,f) sequential 16-lane
// shfl reduce keeps VGPRs flat; partials in ap[w][q][mt][r][f][sd].
template <int KT>
__global__ __launch_bounds__(256, 2) void k_gemm2(const unsigned short* __restrict__ A,
                                                  const unsigned short* __restrict__ Bt,
                                                  unsigned short* __restrict__ C, int M,
                                                  const float* __restrict__ atts, const float* __restrict__ attd,
                                                  float* __restrict__ asA, float* __restrict__ adA) {
    constexpr int NT = KT / 64;
    constexpr int NB = (NT > 1) ? 2 : 1;
    __shared__ v8s As[NB][1024];                 // 128 rows x 8 chunks
    __shared__ v8s Bs[NB][1024];                 // 128 cols x 8 chunks
    __shared__ float ap[4][4][8][4][2][2];       // [w][q][mt][r][f][sd] = 16KB
    const int t = threadIdx.x;
    const int p = blockIdx.x;
    const int bx = (p >> 4) * 8 + (p & 7);
    const int by = (p >> 3) & 1;
    if (bx >= 391) return;
    const int m0 = bx * 128;
    const int n0g = by * 128;
    const int l = t & 63, w = t >> 6;
    const int q = l >> 4, r16 = l & 15;

    const int rr0 = l >> 3;
    const int kc = (l & 7) ^ rr0;

    v4f acc[8][2];
#pragma unroll
    for (int i = 0; i < 8; ++i)
#pragma unroll
        for (int f = 0; f < 2; ++f) acc[i][f] = (v4f){0.f, 0.f, 0.f, 0.f};

    // prologue: stage tile 0
#pragma unroll
    for (int j = 0; j < 4; ++j) {
        int ro = (w * 4 + j) * 8 + rr0;
        gll16(A + (size_t)(m0 + ro) * KT + kc * 8, &As[0][(w * 4 + j) * 64]);
        gll16(Bt + (size_t)(n0g + ro) * KT + kc * 8, &Bs[0][(w * 4 + j) * 64]);
    }
    __syncthreads();
#pragma unroll
    for (int kt = 0; kt < NT; ++kt) {
        const int b = kt & (NB - 1);
        if (kt + 1 < NT) {
            const int nb = (kt + 1) & (NB - 1);
#pragma unroll
            for (int j = 0; j < 4; ++j) {
                int ro = (w * 4 + j) * 8 + rr0;
                gll16(A + (size_t)(m0 + ro) * KT + (kt + 1) * 64 + kc * 8, &As[nb][(w * 4 + j) * 64]);
                gll16(Bt + (size_t)(n0g + ro) * KT + (kt + 1) * 64 + kc * 8, &Bs[nb][(w * 4 + j) * 64]);
            }
        }
#pragma unroll
        for (int s = 0; s < 2; ++s) {
            int c = s * 4 + q;
            int cl0 = w * 16 + r16, cl1 = 64 + w * 16 + r16;
            v8s bfr0 = Bs[b][cl0 * 8 + (c ^ (cl0 & 7))];
            v8s bfr1 = Bs[b][cl1 * 8 + (c ^ (cl1 & 7))];
#pragma unroll
            for (int mt = 0; mt < 8; ++mt) {
                int rl = mt * 16 + r16;
                v8s afr = As[b][rl * 8 + (c ^ (rl & 7))];
                acc[mt][0] = __builtin_amdgcn_mfma_f32_16x16x32_bf16(afr, bfr0, acc[mt][0], 0, 0, 0);
                acc[mt][1] = __builtin_amdgcn_mfma_f32_16x16x32_bf16(afr, bfr1, acc[mt][1], 0, 0, 0);
            }
        }
        __syncthreads();
    }

    // C write (bf16, ldc=256)
#pragma unroll
    for (int mt = 0; mt < 8; ++mt)
#pragma unroll
        for (int f = 0; f < 2; ++f)
#pragma unroll
            for (int r = 0; r < 4; ++r) {
                int row = m0 + mt * 16 + q * 4 + r;
                if (row < M)
                    C[(size_t)row * 256 + n0g + f * 64 + w * 16 + r16] = f2bf(acc[mt][f][r]);
            }

    // ATT epilogue: row-sums of acc*sa / acc*da per head (head = by*2+f)
    float sa0 = atts[n0g + w * 16 + r16],      da0 = attd[n0g + w * 16 + r16];
    float sa1 = atts[n0g + 64 + w * 16 + r16], da1 = attd[n0g + 64 + w * 16 + r16];
#pragma unroll
    for (int mt = 0; mt < 8; ++mt)
#pragma unroll
        for (int f = 0; f < 2; ++f) {
            float sa = f ? sa1 : sa0, da = f ? da1 : da0;
            float xs0 = acc[mt][f][0] * sa, xs1 = acc[mt][f][1] * sa,
                  xs2 = acc[mt][f][2] * sa, xs3 = acc[mt][f][3] * sa;
            float xd0 = acc[mt][f][0] * da, xd1 = acc[mt][f][1] * da,
                  xd2 = acc[mt][f][2] * da, xd3 = acc[mt][f][3] * da;
#pragma unroll
            for (int d = 1; d < 16; d <<= 1) {
                xs0 += __shfl_xor(xs0, d, 64); xs1 += __shfl_xor(xs1, d, 64);
                xs2 += __shfl_xor(xs2, d, 64); xs3 += __shfl_xor(xs3, d, 64);
                xd0 += __shfl_xor(xd0, d, 64); xd1 += __shfl_xor(xd1, d, 64);
                xd2 += __shfl_xor(xd2, d, 64); xd3 += __shfl_xor(xd3, d, 64);
            }
            if (r16 == 0) {
                ap[w][q][mt][0][f][0] = xs0; ap[w][q][mt][1][f][0] = xs1;
                ap[w][q][mt][2][f][0] = xs2; ap[w][q][mt][3][f][0] = xs3;
                ap[w][q][mt][0][f][1] = xd0; ap[w][q][mt][1][f][1] = xd1;
                ap[w][q][mt][2][f][1] = xd2; ap[w][q][mt][3][f][1] = xd3;
            }
        }
    __syncthreads();
    // 128 rows x 2 f x 2 sd: thread t handles (gr = t>>1, sd = t&1), f-loop
    {
        int gr = t >> 1, sd = t & 1;
        int mt = gr >> 4, qq = (gr >> 2) & 3, r = gr & 3;
        if (m0 + gr < M) {
#pragma unroll
            for (int f = 0; f < 2; ++f) {
                float s = (ap[0][qq][mt][r][f][sd] + ap[1][qq][mt][r][f][sd]) +
                          (ap[2][qq][mt][r][f][sd] + ap[3][qq][mt][r][f][sd]);
                (sd ? adA : asA)[(size_t)(m0 + gr) * 4 + by * 2 + f] = s;
            }
        }
    }
}

// R10: fixed-bucket CSR scatter (64 uint16 slots/node), 8-dst-partitioned (R1).
#define SCAT_K 256
__global__ __launch_bounds__(256) void k_scatter(const int* __restrict__ ei, int* __restrict__ cur,
                                                 unsigned short* __restrict__ csr) {
    const int p = blockIdx.x & 7;
    const int j = blockIdx.x >> 3;
    const int plo = p * (NN / 8), phi = plo + (NN / 8);
    const int TOT = EE + NN;
    const int chunk = (TOT + SCAT_K - 1) / SCAT_K;
    const int e1 = min((j + 1) * chunk, TOT);
    for (int e = j * chunk + (int)threadIdx.x; e < e1; e += 256) {
        int d = (e < EE) ? ei[EE + e] : (e - EE);
        if (d < plo || d >= phi) continue;  // drops OOB d too
        int s = (e < EE) ? ei[e] : d;
        if ((unsigned)s >= (unsigned)NN) s = d;
        int pos = atomicAdd(&cur[d], 1);
        if (pos < 64) csr[d * 64 + pos] = (unsigned short)s;
    }
}

// GAT two-phase softmax+aggregate (R7 form) over fixed-bucket CSR.
// ~73us / 208MB FETCH = 8-XCD compulsory-miss floor for the random gather.
__global__ __launch_bounds__(256) void k_agg(const unsigned short* __restrict__ h,
                                             const float* __restrict__ asA, const float* __restrict__ adA,
                                             const int* __restrict__ cur, const unsigned short* __restrict__ csr,
                                             const float* __restrict__ bias,
                                             unsigned short* __restrict__ nout,
                                             const int* __restrict__ batch,
                                             float* __restrict__ gcat, int gbase) {
    __shared__ int   sL[4][64];
    __shared__ float wL[4][64][4];
    __shared__ float mx[4][256];
    __shared__ int   gb[4];
    const int nd4 = threadIdx.x >> 6;
    const int node = blockIdx.x * 4 + nd4;
    const int l = threadIdx.x & 63;
    const int hl = l >> 4, k16 = l & 15;
    const int o0 = node << 6;
    int deg = cur[node]; if (deg > 64) deg = 64;
    const float ad4 = adA[node * 4 + hl];
    float sm = 0.f;
    for (int k = k16; k < deg; k += 16) {
        int s = csr[o0 + k];
        if (hl == 0) sL[nd4][k] = s;
        float e = asA[s * 4 + hl] + ad4;
        e = e > 0.f ? e : 0.2f * e;
        float w = __expf(e);
        wL[nd4][k][hl] = w;
        sm += w;
    }
#pragma unroll
    for (int d = 1; d < 16; d <<= 1) sm += __shfl_xor(sm, d, 64);
    const float rden = 1.f / sm;
    __syncthreads();
    float a0 = 0.f, a1 = 0.f, a2 = 0.f, a3 = 0.f;
    const int c = l * 4;
    int k = 0;
    for (; k + 4 <= deg; k += 4) {
        int s0 = sL[nd4][k], s1 = sL[nd4][k + 1], s2 = sL[nd4][k + 2], s3 = sL[nd4][k + 3];
        float w0 = wL[nd4][k][hl], w1 = wL[nd4][k + 1][hl], w2 = wL[nd4][k + 2][hl], w3 = wL[nd4][k + 3][hl];
        ushort4 h0 = *(const ushort4*)(h + (size_t)s0 * 256 + c);
        ushort4 h1 = *(const ushort4*)(h + (size_t)s1 * 256 + c);
        ushort4 h2 = *(const ushort4*)(h + (size_t)s2 * 256 + c);
        ushort4 h3 = *(const ushort4*)(h + (size_t)s3 * 256 + c);
        a0 += w0 * bf2f(h0.x) + w1 * bf2f(h1.x) + w2 * bf2f(h2.x) + w3 * bf2f(h3.x);
        a1 += w0 * bf2f(h0.y) + w1 * bf2f(h1.y) + w2 * bf2f(h2.y) + w3 * bf2f(h3.y);
        a2 += w0 * bf2f(h0.z) + w1 * bf2f(h1.z) + w2 * bf2f(h2.z) + w3 * bf2f(h3.z);
        a3 += w0 * bf2f(h0.w) + w1 * bf2f(h1.w) + w2 * bf2f(h2.w) + w3 * bf2f(h3.w);
    }
    for (; k < deg; ++k) {
        int s = sL[nd4][k];
        float w = wL[nd4][k][hl];
        ushort4 hv = *(const ushort4*)(h + (size_t)s * 256 + c);
        a0 += w * bf2f(hv.x); a1 += w * bf2f(hv.y); a2 += w * bf2f(hv.z); a3 += w * bf2f(hv.w);
    }
    float4 bv = *(const float4*)(bias + c);
    float v0 = fmaxf(a0 * rden + bv.x, 0.f);
    float v1 = fmaxf(a1 * rden + bv.y, 0.f);
    float v2 = fmaxf(a2 * rden + bv.z, 0.f);
    float v3 = fmaxf(a3 * rden + bv.w, 0.f);
    ushort4 o;
    o.x = f2bf(v0); o.y = f2bf(v1); o.z = f2bf(v2); o.w = f2bf(v3);
    *(ushort4*)(nout + (size_t)node * 256 + c) = o;

    // fused segment-max epilogue
    mx[nd4][c + 0] = v0; mx[nd4][c + 1] = v1; mx[nd4][c + 2] = v2; mx[nd4][c + 3] = v3;
    if (l == 0) gb[nd4] = batch[node];
    __syncthreads();
    const int t = threadIdx.x;
    if (gb[0] == gb[1] && gb[1] == gb[2] && gb[2] == gb[3]) {
        float m = fmaxf(fmaxf(mx[0][t], mx[1][t]), fmaxf(mx[2][t], mx[3][t]));
        atomicMax((int*)(gcat + gb[0] * 832 + gbase + t), __float_as_int(m));
    } else {
        int* g = (int*)(gcat + gb[nd4] * 832 + gbase);
        atomicMax(g + c + 0, __float_as_int(v0));
        atomicMax(g + c + 1, __float_as_int(v1));
        atomicMax(g + c + 2, __float_as_int(v2));
        atomicMax(g + c + 3, __float_as_int(v3));
    }
}

// head stage 1: latent = gcat @ aggW + aggb  (block = 4 graphs x 64 cols, split-K waves)
__global__ __launch_bounds__(256) void k_head1(const float* __restrict__ gcat,
                                               const float* __restrict__ aggW, const float* __restrict__ aggb,
                                               float* __restrict__ latent) {
    __shared__ float gr[832 * 4];      // [k][g]
    __shared__ float part[4][4][64];   // [wave][g][col]
    const int t = threadIdx.x;
    const int g0 = blockIdx.x * 4, c0 = blockIdx.y * 64;
    for (int i = t; i < 832 * 4; i += 256) {
        int k = i >> 2, g = i & 3;
        gr[i] = gcat[(g0 + g) * 832 + k];
    }
    __syncthreads();
    const int w = t >> 6, l = t & 63;
    const float* wp = aggW + c0 + l;
    float a0 = 0.f, a1 = 0.f, a2 = 0.f, a3 = 0.f;
    const int k0 = w * 208;
#pragma unroll 4
    for (int k = k0; k < k0 + 208; ++k) {
        float wv = wp[(size_t)k * 256];
        float4 gv = *(const float4*)&gr[k * 4];
        a0 += gv.x * wv; a1 += gv.y * wv; a2 += gv.z * wv; a3 += gv.w * wv;
    }
    part[w][0][l] = a0; part[w][1][l] = a1; part[w][2][l] = a2; part[w][3][l] = a3;
    __syncthreads();
    const int g = t >> 6, c = t & 63;
    float s = ((part[0][g][c] + part[1][g][c]) + (part[2][g][c] + part[3][g][c])) + aggb[c0 + c];
    latent[(g0 + g) * 256 + c0 + c] = s;
}

// head stage 2: mu/var = latent @ {muW,vaW} + bias
__global__ __launch_bounds__(256) void k_head2(const float* __restrict__ latent,
                                               const float* __restrict__ muW, const float* __restrict__ mub,
                                               const float* __restrict__ vaW, const float* __restrict__ vab,
                                               float* __restrict__ out) {
    __shared__ float lr[256 * 4];      // [k][g]
    __shared__ float pm[4][4][64], pv[4][4][64];
    const int t = threadIdx.x;
    const int g0 = blockIdx.x * 4, c0 = blockIdx.y * 64;
    for (int i = t; i < 256 * 4; i += 256) {
        int k = i >> 2, g = i & 3;
        lr[i] = latent[(g0 + g) * 256 + k];
    }
    __syncthreads();
    const int w = t >> 6, l = t & 63;
    const float* mp = muW + c0 + l;
    const float* vp = vaW + c0 + l;
    float m0 = 0.f, m1 = 0.f, m2 = 0.f, m3 = 0.f;
    float v0 = 0.f, v1 = 0.f, v2 = 0.f, v3 = 0.f;
    const int k0 = w * 64;
#pragma unroll 4
    for (int k = k0; k < k0 + 64; ++k) {
        float wm = mp[(size_t)k * 256];
        float wv = vp[(size_t)k * 256];
        float4 gv = *(const float4*)&lr[k * 4];
        m0 += gv.x * wm; m1 += gv.y * wm; m2 += gv.z * wm; m3 += gv.w * wm;
        v0 += gv.x * wv; v1 += gv.y * wv; v2 += gv.z * wv; v3 += gv.w * wv;
    }
    pm[w][0][l] = m0; pm[w][1][l] = m1; pm[w][2][l] = m2; pm[w][3][l] = m3;
    pv[w][0][l] = v0; pv[w][1][l] = v1; pv[w][2][l] = v2; pv[w][3][l] = v3;
    __syncthreads();
    const int g = t >> 6, c = t & 63;
    float smu = ((pm[0][g][c] + pm[1][g][c]) + (pm[2][g][c] + pm[3][g][c])) + mub[c0 + c];
    float sva = ((pv[0][g][c] + pv[1][g][c]) + (pv[2][g][c] + pv[3][g][c])) + vab[c0 + c];
    out[(g0 + g) * 256 + c0 + c] = smu;
    out[BB * 256 + (g0 + g) * 256 + c0 + c] = sva;
}

extern "C" void kernel_launch(void* const* d_in, const int* in_sizes, int n_in,
                              void* d_out, int out_size, void* d_ws, size_t ws_size,
                              hipStream_t stream) {
    (void)in_sizes; (void)n_in; (void)out_size;
    const float* nf     = (const float*)d_in[0];
    const int*   bmask  = (const int*)d_in[1];
    const int*   batch  = (const int*)d_in[2];
    const int*   ei     = (const int*)d_in[3];
    const float* bboxW  = (const float*)d_in[4];
    const float* bboxb  = (const float*)d_in[5];
    const float* membed = (const float*)d_in[6];
    const float* nodeW  = (const float*)d_in[7];
    const float* nodeb  = (const float*)d_in[8];
    const float* w0     = (const float*)d_in[9];
    const float* as0    = (const float*)d_in[10];
    const float* ad0    = (const float*)d_in[11];
    const float* b0     = (const float*)d_in[12];
    const float* w1     = (const float*)d_in[13];
    const float* as1    = (const float*)d_in[14];
    const float* ad1    = (const float*)d_in[15];
    const float* b1     = (const float*)d_in[16];
    const float* w2     = (const float*)d_in[17];
    const float* as2    = (const float*)d_in[18];
    const float* ad2    = (const float*)d_in[19];
    const float* b2     = (const float*)d_in[20];
    const float* aggW   = (const float*)d_in[21];
    const float* aggb   = (const float*)d_in[22];
    const float* muW    = (const float*)d_in[23];
    const float* mub    = (const float*)d_in[24];
    const float* vaW    = (const float*)d_in[25];
    const float* vab    = (const float*)d_in[26];
    float* out = (float*)d_out;

    char* base = (char*)d_ws;
    unsigned short* hbuf    = (unsigned short*)(base);
    unsigned short* nbuf    = (unsigned short*)(base + 25600000);
    unsigned short* feat128 = nbuf;                                          // overlay
    unsigned short* n0buf   = (unsigned short*)(base + 25600000 + 12800000); // overlay
    char* pool0 = base + 51200000;
    char* p = pool0;
    auto alloc = [&](size_t bytes) { char* r = p; p += (bytes + 255) & ~(size_t)255; return r; };
    unsigned short* nodeWt = (unsigned short*)alloc(128 * 64 * 2);
    unsigned short* w0t    = (unsigned short*)alloc(64 * 256 * 2);
    unsigned short* w1t    = (unsigned short*)alloc(256 * 256 * 2);
    unsigned short* w2t    = (unsigned short*)alloc(256 * 256 * 2);
    float* asA    = (float*)alloc((size_t)NN * 4 * 4);
    float* adA    = (float*)alloc((size_t)NN * 4 * 4);
    int*   cur    = (int*)alloc((size_t)NN * 4);
    unsigned short* csr = (unsigned short*)alloc((size_t)NN * 64 * 2);
    float* gcat   = (float*)alloc((size_t)BB * 832 * 4);
    float* latent = (float*)alloc((size_t)BB * 256 * 4);
    char*  tailpad = alloc(64 * 1024);  // guard: 128-row M-tail reads past nbuf
    (void)tailpad;
    const size_t NEED = (size_t)(p - base);

    if (ws_size < NEED) {
        k_sentinel<<<1000, 256, 0, stream>>>(out, 2000.0f + (float)(ws_size >> 20));
        return;
    }

    k_prep<<<(NN * 64 + 155648 + BB * 832 + 255) / 256, 256, 0, stream>>>(
        nf, bmask, bboxW, bboxb, membed, feat128,
        nodeW, nodeWt, w0, w0t, w1, w1t, w2, w2t, cur, gcat);
    // CSR: fixed buckets, no count/scan
    k_scatter<<<SCAT_K * 8, 256, 0, stream>>>(ei, cur, csr);
    // n0  (782 blocks, fused segment-max epilogue)
    k_gemm<128><<<782, 256, 0, stream>>>(feat128, nodeWt, nodeb, n0buf, NN, 64, batch, gcat);
    // layer 0 (128x128-tile ATT gemm)
    k_gemm2<64><<<784, 256, 0, stream>>>(n0buf, w0t, hbuf, NN, as0, ad0, asA, adA);
    k_agg<<<12500, 256, 0, stream>>>(hbuf, asA, adA, cur, csr, b0, nbuf, batch, gcat, 64);
    // layer 1
    k_gemm2<256><<<784, 256, 0, stream>>>(nbuf, w1t, hbuf, NN, as1, ad1, asA, adA);
    k_agg<<<12500, 256, 0, stream>>>(hbuf, asA, adA, cur, csr, b1, nbuf, batch, gcat, 320);
    // layer 2
    k_gemm2<256><<<784, 256, 0, stream>>>(nbuf, w2t, hbuf, NN, as2, ad2, asA, adA);
    k_agg<<<12500, 256, 0, stream>>>(hbuf, asA, adA, cur, csr, b2, nbuf, batch, gcat, 576);
    // head: two split-K stages
    k_head1<<<dim3(BB / 4, 4), 256, 0, stream>>>(gcat, aggW, aggb, latent);
    k_head2<<<dim3(BB / 4, 4), 256, 0, stream>>>(latent, muW, mub, vaW, vab, out);
}

// Round 13
// 545.989 us; speedup vs baseline: 1.0293x; 1.0293x over previous
//
#include <hip/hip_runtime.h>

#define NN 50000
#define EE 800000
#define BB 500

typedef short v8s __attribute__((ext_vector_type(8)));
typedef float v4f __attribute__((ext_vector_type(4)));

__device__ __forceinline__ float bf2f(unsigned short u) {
    union { unsigned int i; float f; } v; v.i = ((unsigned int)u) << 16; return v.f;
}
__device__ __forceinline__ unsigned short f2bf(float f) {
    union { float f; unsigned int i; } v; v.f = f;
    unsigned int x = v.i;
    unsigned int r = (x + 0x7FFFu + ((x >> 16) & 1u)) >> 16;
    return (unsigned short)r;
}

// async global->LDS, 16B per lane; dst must be wave-uniform base (HW adds lane*16)
__device__ __forceinline__ void gll16(const unsigned short* g, v8s* l) {
    __builtin_amdgcn_global_load_lds((const __attribute__((address_space(1))) unsigned int*)g,
                                     (__attribute__((address_space(3))) unsigned int*)l, 16, 0, 0);
}

__global__ void k_sentinel(float* out, float val) {
    int i = blockIdx.x * blockDim.x + threadIdx.x;
    if (i < BB * 512) out[i] = val;
}

// fused: cursor init + node featurization + weight transposes + gcat zero (full 832)
__global__ void k_prep(const float* __restrict__ nf, const int* __restrict__ bmask,
                       const float* __restrict__ bboxW, const float* __restrict__ bboxb,
                       const float* __restrict__ membed, unsigned short* __restrict__ feat,
                       const float* __restrict__ a0, unsigned short* __restrict__ d0,
                       const float* __restrict__ a1, unsigned short* __restrict__ d1,
                       const float* __restrict__ a2, unsigned short* __restrict__ d2,
                       const float* __restrict__ a3, unsigned short* __restrict__ d3,
                       int* __restrict__ cur, float* __restrict__ gcat) {
    int g = blockIdx.x * blockDim.x + threadIdx.x;
    if (g < NN) cur[g] = 0;
    if (g < NN * 64) {
        int n = g >> 6, f = g & 63;
        float s = bboxb[f];
        for (int k = 0; k < 5; ++k) s += nf[n * 5 + k] * bboxW[k * 64 + f];
        s = fmaxf(s, 0.f);
        int bm = bmask[n]; if ((unsigned)bm > 1u) bm = 0;
        float mv = fmaxf(membed[bm * 64 + f], 0.f);
        feat[(size_t)n * 128 + f] = f2bf(s);
        feat[(size_t)n * 128 + 64 + f] = f2bf(mv);
        return;
    }
    g -= NN * 64;
    if (g >= 155648) {
        if (g < 155648 + BB * 832) {
            int idx = g - 155648;
            gcat[idx] = 0.f;  // atomicMax target init (all 832 cols)
        }
        return;
    }
    const float* in; unsigned short* out; int K, Nout, idx;
    if (g < 8192)        { in = a0; out = d0; K = 128; Nout = 64;  idx = g; }
    else if (g < 24576)  { in = a1; out = d1; K = 64;  Nout = 256; idx = g - 8192; }
    else if (g < 90112)  { in = a2; out = d2; K = 256; Nout = 256; idx = g - 24576; }
    else                 { in = a3; out = d3; K = 256; Nout = 256; idx = g - 90112; }
    int k = idx / Nout, n = idx % Nout;
    out[n * K + k] = f2bf(in[idx]);
}

// n0 GEMM (64x64 tile, R4/R5 form) with fused segment-max epilogue (R10).
template <int KT>
__global__ __launch_bounds__(256) void k_gemm(const unsigned short* __restrict__ A,
                                              const unsigned short* __restrict__ Bt,
                                              const float* __restrict__ bias,
                                              unsigned short* __restrict__ C, int M, int ldc,
                                              const int* __restrict__ batch, float* __restrict__ gmax) {
    constexpr int NT = KT / 64;
    constexpr int NB = (NT > 1) ? 2 : 1;
    __shared__ v8s As[NB][512];
    __shared__ v8s Bs[NB][512];
    const int t = threadIdx.x;
    const int bx = blockIdx.x;
    const int m0 = bx * 64;
    const int l = t & 63, w = t >> 6;
    const int q = l >> 4, r16 = l & 15;
    const int nloc = w * 16 + r16;

    const int roff0 = (w * 2 + 0) * 8 + (l >> 3);
    const int roff1 = (w * 2 + 1) * 8 + (l >> 3);
    const int kc = (l & 7) ^ (l >> 3);
    const unsigned short* Asrc0 = A + (size_t)(m0 + roff0) * KT + kc * 8;
    const unsigned short* Asrc1 = A + (size_t)(m0 + roff1) * KT + kc * 8;
    const unsigned short* Bsrc0 = Bt + (size_t)roff0 * KT + kc * 8;
    const unsigned short* Bsrc1 = Bt + (size_t)roff1 * KT + kc * 8;

    v4f acc[4];
#pragma unroll
    for (int i = 0; i < 4; ++i) acc[i] = (v4f){0.f, 0.f, 0.f, 0.f};

    gll16(Asrc0, &As[0][(w * 2 + 0) * 64]);
    gll16(Asrc1, &As[0][(w * 2 + 1) * 64]);
    gll16(Bsrc0, &Bs[0][(w * 2 + 0) * 64]);
    gll16(Bsrc1, &Bs[0][(w * 2 + 1) * 64]);
    __syncthreads();
#pragma unroll
    for (int kt = 0; kt < NT; ++kt) {
        const int b = kt & (NB - 1);
        if (kt + 1 < NT) {
            const int nb = (kt + 1) & (NB - 1);
            gll16(Asrc0 + (kt + 1) * 64, &As[nb][(w * 2 + 0) * 64]);
            gll16(Asrc1 + (kt + 1) * 64, &As[nb][(w * 2 + 1) * 64]);
            gll16(Bsrc0 + (kt + 1) * 64, &Bs[nb][(w * 2 + 0) * 64]);
            gll16(Bsrc1 + (kt + 1) * 64, &Bs[nb][(w * 2 + 1) * 64]);
        }
#pragma unroll
        for (int s = 0; s < 2; ++s) {
            int c = s * 4 + q;
            v8s bfr = Bs[b][nloc * 8 + (c ^ (nloc & 7))];
#pragma unroll
            for (int mt = 0; mt < 4; ++mt) {
                v8s afr = As[b][(mt * 16 + r16) * 8 + (c ^ (r16 & 7))];
                acc[mt] = __builtin_amdgcn_mfma_f32_16x16x32_bf16(afr, bfr, acc[mt], 0, 0, 0);
            }
        }
        __syncthreads();
    }

    const int col = nloc;
#pragma unroll
    for (int mt = 0; mt < 4; ++mt) {
#pragma unroll
        for (int r = 0; r < 4; ++r) {
            int row = m0 + mt * 16 + q * 4 + r;
            if (row < M) {
                float v = fmaxf(acc[mt][r] + bias[col], 0.f);
                C[(size_t)row * ldc + col] = f2bf(v);
                atomicMax((int*)(gmax + (size_t)batch[row] * 832 + col), __float_as_int(v));
            }
        }
    }
}

// R12: ATT layer GEMM, 64x64 tile (R10 shape/occupancy: 4 blocks/CU) with
// B-IN-REGISTERS: B (<=128KB) is L2-resident on every XCD, so staging it
// through LDS was pure overhead. Each lane loads its output-column's 2*NT
// B-fragments (16B each) ONCE at block start; MFMAs consume bq[kt*2+s] from
// VGPRs. Removes all B gll16s + B LDS reads; barrier now drains A only.
// LDS 34->18KB; ~+32 VGPR. Grid/XCD mapping, ATT epilogue: identical to R10.
// (R11's 128x128 tile REVERTED: 80KB LDS -> 2 blocks/CU halved latency
// hiding, +16us total. Occupancy > tile size for these latency-bound gemms.)
template <int KT>
__global__ __launch_bounds__(256) void k_gemm2(const unsigned short* __restrict__ A,
                                               const unsigned short* __restrict__ Bt,
                                               unsigned short* __restrict__ C, int M,
                                               const float* __restrict__ atts, const float* __restrict__ attd,
                                               float* __restrict__ asA, float* __restrict__ adA, int nbx) {
    constexpr int NT = KT / 64;
    constexpr int NB = (NT > 1) ? 2 : 1;
    __shared__ v8s As[NB][512];
    __shared__ float ap[4][4][4][4][2];
    const int t = threadIdx.x;
    int p = blockIdx.x;
    int gidx = p >> 5, r = p & 31;
    int bx = gidx * 8 + (r & 7);
    int by = r >> 3;
    if (bx >= nbx) return;
    const int m0 = bx * 64;
    const int n0g = by * 64;
    const int l = t & 63, w = t >> 6;
    const int q = l >> 4, r16 = l & 15;
    const int nloc = w * 16 + r16;

    // B fragments -> registers (once per block; rows scattered but L2-hit)
    v8s bq[2 * NT];
    const unsigned short* Brow = Bt + (size_t)(n0g + nloc) * KT;
#pragma unroll
    for (int i = 0; i < 2 * NT; ++i) {
        int chunk = (i >> 1) * 8 + (i & 1) * 4 + q;   // kt*8 + s*4 + q
        bq[i] = *(const v8s*)(Brow + chunk * 8);
    }

    const int roff0 = (w * 2 + 0) * 8 + (l >> 3);
    const int roff1 = (w * 2 + 1) * 8 + (l >> 3);
    const int kc = (l & 7) ^ (l >> 3);
    const unsigned short* Asrc0 = A + (size_t)(m0 + roff0) * KT + kc * 8;
    const unsigned short* Asrc1 = A + (size_t)(m0 + roff1) * KT + kc * 8;

    v4f acc[4];
#pragma unroll
    for (int i = 0; i < 4; ++i) acc[i] = (v4f){0.f, 0.f, 0.f, 0.f};

    gll16(Asrc0, &As[0][(w * 2 + 0) * 64]);
    gll16(Asrc1, &As[0][(w * 2 + 1) * 64]);
    __syncthreads();
#pragma unroll
    for (int kt = 0; kt < NT; ++kt) {
        const int b = kt & (NB - 1);
        if (kt + 1 < NT) {
            const int nb = (kt + 1) & (NB - 1);
            gll16(Asrc0 + (kt + 1) * 64, &As[nb][(w * 2 + 0) * 64]);
            gll16(Asrc1 + (kt + 1) * 64, &As[nb][(w * 2 + 1) * 64]);
        }
#pragma unroll
        for (int s = 0; s < 2; ++s) {
            int c = s * 4 + q;
            v8s bfr = bq[kt * 2 + s];
#pragma unroll
            for (int mt = 0; mt < 4; ++mt) {
                v8s afr = As[b][(mt * 16 + r16) * 8 + (c ^ (r16 & 7))];
                acc[mt] = __builtin_amdgcn_mfma_f32_16x16x32_bf16(afr, bfr, acc[mt], 0, 0, 0);
            }
        }
        __syncthreads();
    }

    const int col = n0g + nloc;
#pragma unroll
    for (int mt = 0; mt < 4; ++mt) {
#pragma unroll
        for (int r = 0; r < 4; ++r) {
            int row = m0 + mt * 16 + q * 4 + r;
            if (row < M)
                C[(size_t)row * 256 + col] = f2bf(acc[mt][r]);
        }
    }
    // ATT epilogue (R10 form)
    {
        float sa = atts[col];
        float da = attd[col];
        float rs[4][4], rd[4][4];
#pragma unroll
        for (int mt = 0; mt < 4; ++mt)
#pragma unroll
            for (int rr = 0; rr < 4; ++rr) { rs[mt][rr] = acc[mt][rr] * sa; rd[mt][rr] = acc[mt][rr] * da; }
#pragma unroll
        for (int d = 1; d < 16; d <<= 1) {
#pragma unroll
            for (int mt = 0; mt < 4; ++mt)
#pragma unroll
                for (int rr = 0; rr < 4; ++rr) {
                    rs[mt][rr] += __shfl_xor(rs[mt][rr], d, 64);
                    rd[mt][rr] += __shfl_xor(rd[mt][rr], d, 64);
                }
        }
        if (r16 == 0) {
#pragma unroll
            for (int mt = 0; mt < 4; ++mt)
#pragma unroll
                for (int rr = 0; rr < 4; ++rr) { ap[w][q][mt][rr][0] = rs[mt][rr]; ap[w][q][mt][rr][1] = rd[mt][rr]; }
        }
        __syncthreads();
        if (t < 128) {
            int row = t >> 1, which = t & 1;
            int qq = (row >> 2) & 3, mtt = row >> 4, rr = row & 3;
            float s = ap[0][qq][mtt][rr][which] + ap[1][qq][mtt][rr][which] +
                      ap[2][qq][mtt][rr][which] + ap[3][qq][mtt][rr][which];
            if (m0 + row < M) (which ? adA : asA)[(m0 + row) * 4 + by] = s;
        }
    }
}

// R10: fixed-bucket CSR scatter (64 uint16 slots/node), 8-dst-partitioned (R1).
#define SCAT_K 256
__global__ __launch_bounds__(256) void k_scatter(const int* __restrict__ ei, int* __restrict__ cur,
                                                 unsigned short* __restrict__ csr) {
    const int p = blockIdx.x & 7;
    const int j = blockIdx.x >> 3;
    const int plo = p * (NN / 8), phi = plo + (NN / 8);
    const int TOT = EE + NN;
    const int chunk = (TOT + SCAT_K - 1) / SCAT_K;
    const int e1 = min((j + 1) * chunk, TOT);
    for (int e = j * chunk + (int)threadIdx.x; e < e1; e += 256) {
        int d = (e < EE) ? ei[EE + e] : (e - EE);
        if (d < plo || d >= phi) continue;  // drops OOB d too
        int s = (e < EE) ? ei[e] : d;
        if ((unsigned)s >= (unsigned)NN) s = d;
        int pos = atomicAdd(&cur[d], 1);
        if (pos < 64) csr[d * 64 + pos] = (unsigned short)s;
    }
}

// GAT two-phase softmax+aggregate (R7 form) over fixed-bucket CSR.
// ~73us / 208MB FETCH = 8-XCD compulsory-miss floor for the random gather.
__global__ __launch_bounds__(256) void k_agg(const unsigned short* __restrict__ h,
                                             const float* __restrict__ asA, const float* __restrict__ adA,
                                             const int* __restrict__ cur, const unsigned short* __restrict__ csr,
                                             const float* __restrict__ bias,
                                             unsigned short* __restrict__ nout,
                                             const int* __restrict__ batch,
                                             float* __restrict__ gcat, int gbase) {
    __shared__ int   sL[4][64];
    __shared__ float wL[4][64][4];
    __shared__ float mx[4][256];
    __shared__ int   gb[4];
    const int nd4 = threadIdx.x >> 6;
    const int node = blockIdx.x * 4 + nd4;
    const int l = threadIdx.x & 63;
    const int hl = l >> 4, k16 = l & 15;
    const int o0 = node << 6;
    int deg = cur[node]; if (deg > 64) deg = 64;
    const float ad4 = adA[node * 4 + hl];
    float sm = 0.f;
    for (int k = k16; k < deg; k += 16) {
        int s = csr[o0 + k];
        if (hl == 0) sL[nd4][k] = s;
        float e = asA[s * 4 + hl] + ad4;
        e = e > 0.f ? e : 0.2f * e;
        float w = __expf(e);
        wL[nd4][k][hl] = w;
        sm += w;
    }
#pragma unroll
    for (int d = 1; d < 16; d <<= 1) sm += __shfl_xor(sm, d, 64);
    const float rden = 1.f / sm;
    __syncthreads();
    float a0 = 0.f, a1 = 0.f, a2 = 0.f, a3 = 0.f;
    const int c = l * 4;
    int k = 0;
    for (; k + 4 <= deg; k += 4) {
        int s0 = sL[nd4][k], s1 = sL[nd4][k + 1], s2 = sL[nd4][k + 2], s3 = sL[nd4][k + 3];
        float w0 = wL[nd4][k][hl], w1 = wL[nd4][k + 1][hl], w2 = wL[nd4][k + 2][hl], w3 = wL[nd4][k + 3][hl];
        ushort4 h0 = *(const ushort4*)(h + (size_t)s0 * 256 + c);
        ushort4 h1 = *(const ushort4*)(h + (size_t)s1 * 256 + c);
        ushort4 h2 = *(const ushort4*)(h + (size_t)s2 * 256 + c);
        ushort4 h3 = *(const ushort4*)(h + (size_t)s3 * 256 + c);
        a0 += w0 * bf2f(h0.x) + w1 * bf2f(h1.x) + w2 * bf2f(h2.x) + w3 * bf2f(h3.x);
        a1 += w0 * bf2f(h0.y) + w1 * bf2f(h1.y) + w2 * bf2f(h2.y) + w3 * bf2f(h3.y);
        a2 += w0 * bf2f(h0.z) + w1 * bf2f(h1.z) + w2 * bf2f(h2.z) + w3 * bf2f(h3.z);
        a3 += w0 * bf2f(h0.w) + w1 * bf2f(h1.w) + w2 * bf2f(h2.w) + w3 * bf2f(h3.w);
    }
    for (; k < deg; ++k) {
        int s = sL[nd4][k];
        float w = wL[nd4][k][hl];
        ushort4 hv = *(const ushort4*)(h + (size_t)s * 256 + c);
        a0 += w * bf2f(hv.x); a1 += w * bf2f(hv.y); a2 += w * bf2f(hv.z); a3 += w * bf2f(hv.w);
    }
    float4 bv = *(const float4*)(bias + c);
    float v0 = fmaxf(a0 * rden + bv.x, 0.f);
    float v1 = fmaxf(a1 * rden + bv.y, 0.f);
    float v2 = fmaxf(a2 * rden + bv.z, 0.f);
    float v3 = fmaxf(a3 * rden + bv.w, 0.f);
    ushort4 o;
    o.x = f2bf(v0); o.y = f2bf(v1); o.z = f2bf(v2); o.w = f2bf(v3);
    *(ushort4*)(nout + (size_t)node * 256 + c) = o;

    // fused segment-max epilogue
    mx[nd4][c + 0] = v0; mx[nd4][c + 1] = v1; mx[nd4][c + 2] = v2; mx[nd4][c + 3] = v3;
    if (l == 0) gb[nd4] = batch[node];
    __syncthreads();
    const int t = threadIdx.x;
    if (gb[0] == gb[1] && gb[1] == gb[2] && gb[2] == gb[3]) {
        float m = fmaxf(fmaxf(mx[0][t], mx[1][t]), fmaxf(mx[2][t], mx[3][t]));
        atomicMax((int*)(gcat + gb[0] * 832 + gbase + t), __float_as_int(m));
    } else {
        int* g = (int*)(gcat + gb[nd4] * 832 + gbase);
        atomicMax(g + c + 0, __float_as_int(v0));
        atomicMax(g + c + 1, __float_as_int(v1));
        atomicMax(g + c + 2, __float_as_int(v2));
        atomicMax(g + c + 3, __float_as_int(v3));
    }
}

// head stage 1: latent = gcat @ aggW + aggb  (block = 4 graphs x 64 cols, split-K waves)
__global__ __launch_bounds__(256) void k_head1(const float* __restrict__ gcat,
                                               const float* __restrict__ aggW, const float* __restrict__ aggb,
                                               float* __restrict__ latent) {
    __shared__ float gr[832 * 4];      // [k][g]
    __shared__ float part[4][4][64];   // [wave][g][col]
    const int t = threadIdx.x;
    const int g0 = blockIdx.x * 4, c0 = blockIdx.y * 64;
    for (int i = t; i < 832 * 4; i += 256) {
        int k = i >> 2, g = i & 3;
        gr[i] = gcat[(g0 + g) * 832 + k];
    }
    __syncthreads();
    const int w = t >> 6, l = t & 63;
    const float* wp = aggW + c0 + l;
    float a0 = 0.f, a1 = 0.f, a2 = 0.f, a3 = 0.f;
    const int k0 = w * 208;
#pragma unroll 4
    for (int k = k0; k < k0 + 208; ++k) {
        float wv = wp[(size_t)k * 256];
        float4 gv = *(const float4*)&gr[k * 4];
        a0 += gv.x * wv; a1 += gv.y * wv; a2 += gv.z * wv; a3 += gv.w * wv;
    }
    part[w][0][l] = a0; part[w][1][l] = a1; part[w][2][l] = a2; part[w][3][l] = a3;
    __syncthreads();
    const int g = t >> 6, c = t & 63;
    float s = ((part[0][g][c] + part[1][g][c]) + (part[2][g][c] + part[3][g][c])) + aggb[c0 + c];
    latent[(g0 + g) * 256 + c0 + c] = s;
}

// head stage 2: mu/var = latent @ {muW,vaW} + bias
__global__ __launch_bounds__(256) void k_head2(const float* __restrict__ latent,
                                               const float* __restrict__ muW, const float* __restrict__ mub,
                                               const float* __restrict__ vaW, const float* __restrict__ vab,
                                               float* __restrict__ out) {
    __shared__ float lr[256 * 4];      // [k][g]
    __shared__ float pm[4][4][64], pv[4][4][64];
    const int t = threadIdx.x;
    const int g0 = blockIdx.x * 4, c0 = blockIdx.y * 64;
    for (int i = t; i < 256 * 4; i += 256) {
        int k = i >> 2, g = i & 3;
        lr[i] = latent[(g0 + g) * 256 + k];
    }
    __syncthreads();
    const int w = t >> 6, l = t & 63;
    const float* mp = muW + c0 + l;
    const float* vp = vaW + c0 + l;
    float m0 = 0.f, m1 = 0.f, m2 = 0.f, m3 = 0.f;
    float v0 = 0.f, v1 = 0.f, v2 = 0.f, v3 = 0.f;
    const int k0 = w * 64;
#pragma unroll 4
    for (int k = k0; k < k0 + 64; ++k) {
        float wm = mp[(size_t)k * 256];
        float wv = vp[(size_t)k * 256];
        float4 gv = *(const float4*)&lr[k * 4];
        m0 += gv.x * wm; m1 += gv.y * wm; m2 += gv.z * wm; m3 += gv.w * wm;
        v0 += gv.x * wv; v1 += gv.y * wv; v2 += gv.z * wv; v3 += gv.w * wv;
    }
    pm[w][0][l] = m0; pm[w][1][l] = m1; pm[w][2][l] = m2; pm[w][3][l] = m3;
    pv[w][0][l] = v0; pv[w][1][l] = v1; pv[w][2][l] = v2; pv[w][3][l] = v3;
    __syncthreads();
    const int g = t >> 6, c = t & 63;
    float smu = ((pm[0][g][c] + pm[1][g][c]) + (pm[2][g][c] + pm[3][g][c])) + mub[c0 + c];
    float sva = ((pv[0][g][c] + pv[1][g][c]) + (pv[2][g][c] + pv[3][g][c])) + vab[c0 + c];
    out[(g0 + g) * 256 + c0 + c] = smu;
    out[BB * 256 + (g0 + g) * 256 + c0 + c] = sva;
}

extern "C" void kernel_launch(void* const* d_in, const int* in_sizes, int n_in,
                              void* d_out, int out_size, void* d_ws, size_t ws_size,
                              hipStream_t stream) {
    (void)in_sizes; (void)n_in; (void)out_size;
    const float* nf     = (const float*)d_in[0];
    const int*   bmask  = (const int*)d_in[1];
    const int*   batch  = (const int*)d_in[2];
    const int*   ei     = (const int*)d_in[3];
    const float* bboxW  = (const float*)d_in[4];
    const float* bboxb  = (const float*)d_in[5];
    const float* membed = (const float*)d_in[6];
    const float* nodeW  = (const float*)d_in[7];
    const float* nodeb  = (const float*)d_in[8];
    const float* w0     = (const float*)d_in[9];
    const float* as0    = (const float*)d_in[10];
    const float* ad0    = (const float*)d_in[11];
    const float* b0     = (const float*)d_in[12];
    const float* w1     = (const float*)d_in[13];
    const float* as1    = (const float*)d_in[14];
    const float* ad1    = (const float*)d_in[15];
    const float* b1     = (const float*)d_in[16];
    const float* w2     = (const float*)d_in[17];
    const float* as2    = (const float*)d_in[18];
    const float* ad2    = (const float*)d_in[19];
    const float* b2     = (const float*)d_in[20];
    const float* aggW   = (const float*)d_in[21];
    const float* aggb   = (const float*)d_in[22];
    const float* muW    = (const float*)d_in[23];
    const float* mub    = (const float*)d_in[24];
    const float* vaW    = (const float*)d_in[25];
    const float* vab    = (const float*)d_in[26];
    float* out = (float*)d_out;

    char* base = (char*)d_ws;
    unsigned short* hbuf    = (unsigned short*)(base);
    unsigned short* nbuf    = (unsigned short*)(base + 25600000);
    unsigned short* feat128 = nbuf;                                          // overlay
    unsigned short* n0buf   = (unsigned short*)(base + 25600000 + 12800000); // overlay
    char* pool0 = base + 51200000;
    char* p = pool0;
    auto alloc = [&](size_t bytes) { char* r = p; p += (bytes + 255) & ~(size_t)255; return r; };
    unsigned short* nodeWt = (unsigned short*)alloc(128 * 64 * 2);
    unsigned short* w0t    = (unsigned short*)alloc(64 * 256 * 2);
    unsigned short* w1t    = (unsigned short*)alloc(256 * 256 * 2);
    unsigned short* w2t    = (unsigned short*)alloc(256 * 256 * 2);
    float* asA    = (float*)alloc((size_t)NN * 4 * 4);
    float* adA    = (float*)alloc((size_t)NN * 4 * 4);
    int*   cur    = (int*)alloc((size_t)NN * 4);
    unsigned short* csr = (unsigned short*)alloc((size_t)NN * 64 * 2);
    float* gcat   = (float*)alloc((size_t)BB * 832 * 4);
    float* latent = (float*)alloc((size_t)BB * 256 * 4);
    const size_t NEED = (size_t)(p - base);

    if (ws_size < NEED) {
        k_sentinel<<<1000, 256, 0, stream>>>(out, 2000.0f + (float)(ws_size >> 20));
        return;
    }

    k_prep<<<(NN * 64 + 155648 + BB * 832 + 255) / 256, 256, 0, stream>>>(
        nf, bmask, bboxW, bboxb, membed, feat128,
        nodeW, nodeWt, w0, w0t, w1, w1t, w2, w2t, cur, gcat);
    // CSR: fixed buckets, no count/scan
    k_scatter<<<SCAT_K * 8, 256, 0, stream>>>(ei, cur, csr);
    // n0  (782 blocks, fused segment-max epilogue)
    k_gemm<128><<<782, 256, 0, stream>>>(feat128, nodeWt, nodeb, n0buf, NN, 64, batch, gcat);
    // layer 0 (64x64 tile, B-in-registers)
    k_gemm2<64><<<3136, 256, 0, stream>>>(n0buf, w0t, hbuf, NN, as0, ad0, asA, adA, 782);
    k_agg<<<12500, 256, 0, stream>>>(hbuf, asA, adA, cur, csr, b0, nbuf, batch, gcat, 64);
    // layer 1
    k_gemm2<256><<<3136, 256, 0, stream>>>(nbuf, w1t, hbuf, NN, as1, ad1, asA, adA, 782);
    k_agg<<<12500, 256, 0, stream>>>(hbuf, asA, adA, cur, csr, b1, nbuf, batch, gcat, 320);
    // layer 2
    k_gemm2<256><<<3136, 256, 0, stream>>>(nbuf, w2t, hbuf, NN, as2, ad2, asA, adA, 782);
    k_agg<<<12500, 256, 0, stream>>>(hbuf, asA, adA, cur, csr, b2, nbuf, batch, gcat, 576);
    // head: two split-K stages
    k_head1<<<dim3(BB / 4, 4), 256, 0, stream>>>(gcat, aggW, aggb, latent);
    k_head2<<<dim3(BB / 4, 4), 256, 0, stream>>>(latent, muW, mub, vaW, vab, out);
}